// Round 2
// baseline (93.624 us; speedup 1.0000x reference)
//
#include <hip/hip_runtime.h>
#include <hip/hip_fp16.h>
#include <stdint.h>

// ---------------------------------------------------------------------------
// BareKANLayer: out[b,o] = sum_d PCHIP_interp(x[b,d]; coeffs[o,d,:]) + bias[o]
// B=8192, O=64, D=64, K=64, grid [-2,2], h = 4/63.
//
// Table: per (d, interval i, o) cubic coeffs of p(u) = c0 + c1 u + c2 u^2 + c3 u^3
// packed as fp16 in a uint2: .x = (h(c1)<<16)|h(c0), .y = (h(c3)<<16)|h(c2).
// Row i=63 is a LINEAR row for right extrapolation. Left extrap = row 0, w2=w3=0.
// Layout: T[d][i][o], slice per d = 64*64*8 = 32 KB, total 2 MB in d_ws.
//
// Round-2 restructure: Round-1's null result (4x MLP, no change) showed the
// bottleneck is the 268 MB random-gather stream through L1/L2 (~8 TB/s random
// L2 BW). New kan_main tiles B x D: block = (256 b's) x (8 d's), stages table
// d-slices into LDS (64 KB chunk, 4 chunks), serves all gathers from LDS
// (69 TB/s). Global table traffic: 268 MB random -> 64 MB streamed. Cross-
// d-group sum via 8-plane partial buffer + small reduce kernel.
// ---------------------------------------------------------------------------

typedef _Float16 half2v __attribute__((ext_vector_type(2)));

#if defined(__has_builtin)
#if __has_builtin(__builtin_amdgcn_fdot2)
#define HAS_FDOT2 1
#endif
#endif

__device__ __forceinline__ uint32_t h16(float f) {
    return (uint32_t)__half_as_ushort(__float2half(f));   // RNE cvt
}

__device__ __forceinline__ float dot2acc(uint32_t a_bits, uint32_t b_bits, float acc) {
    half2v a = __builtin_bit_cast(half2v, a_bits);
    half2v b = __builtin_bit_cast(half2v, b_bits);
#ifdef HAS_FDOT2
    return __builtin_amdgcn_fdot2(a, b, acc, false);
#else
    return acc + (float)a.x * (float)b.x + (float)a.y * (float)b.y;
#endif
}

// Grid: 256 blocks (d = bx>>2, o-quarter = bx&3), 256 threads.  (UNCHANGED)
__global__ void build_table(const float* __restrict__ coeffs, uint2* __restrict__ T) {
    const float hf = 4.0f / 63.0f;
    const float inv_hf = 63.0f / 4.0f;   // 15.75 exact in fp32
    int d  = blockIdx.x >> 2;
    int ob = (blockIdx.x & 3) << 4;      // base of this block's 16 o's
    __shared__ float Y[16][65];          // +1 pad: conflict-free
    int t = threadIdx.x;
    {
        int ol = t >> 4;                 // 0..15  (o local)
        int k4 = (t & 15) << 2;          // 0,4,...,60
        const float* src = coeffs + (size_t)(ob + ol) * 4096 + d * 64 + k4;
        float4 v = *(const float4*)src;  // 16B aligned
        Y[ol][k4 + 0] = v.x; Y[ol][k4 + 1] = v.y;
        Y[ol][k4 + 2] = v.z; Y[ol][k4 + 3] = v.w;
    }
    __syncthreads();
    for (int c = t; c < 1024; c += 256) {
        int ol = c & 15;
        int i  = c >> 4;                 // 0..63 (63 = linear extrapolation row)
        const float* Yr = Y[ol];
        auto delt = [&](int k) -> float { return (Yr[k + 1] - Yr[k]) * inv_hf; };
        auto endslope = [&](float a, float b) -> float {
            float de = (3.0f * a - b) * 0.5f;
            de = (de * a <= 0.0f) ? 0.0f : de;
            de = ((a * b < 0.0f) && (fabsf(de) > 3.0f * fabsf(a))) ? 3.0f * a : de;
            return de;
        };
        auto slope = [&](int k) -> float {
            if (k == 0)  return endslope(delt(0), delt(1));
            if (k == 63) return endslope(delt(62), delt(61));
            float dp = delt(k - 1), dn = delt(k);
            return (dp * dn > 0.0f) ? (2.0f * dp * dn) / (dp + dn + 1e-12f) : 0.0f;
        };
        uint2 pk;
        if (i < 63) {
            float y0 = Yr[i], y1 = Yr[i + 1];
            float di = slope(i), dj = slope(i + 1);
            float c0 = y0;
            float c1 = hf * di;
            float c2 = 3.0f * (y1 - y0) - hf * (2.0f * di + dj);
            float c3 = 2.0f * (y0 - y1) + hf * (di + dj);
            pk.x = (h16(c1) << 16) | h16(c0);
            pk.y = (h16(c3) << 16) | h16(c2);
        } else {
            float yN = Yr[63];
            float dN = slope(63);
            pk.x = (h16(hf * dN) << 16) | h16(yN);
            pk.y = 0u;
        }
        T[(size_t)d * 4096 + i * 64 + (ob + ol)] = pk;
    }
}

// Grid: 256 blocks x 512 threads (8 waves).
// Block: p = bx&7 selects d-group [8p, 8p+8); btile = bx>>3 selects 256 b's.
// Wave wv owns 32 b's; lane = o. Table chunk (2 d-slices, 64 KB) staged in LDS
// via global_load_lds; weight records precomputed once into LDS (32 KB).
__global__ void __launch_bounds__(512) kan_main(const float* __restrict__ x,
                                                const char* __restrict__ Tb,
                                                float* __restrict__ part) {
    __shared__ char  TL[65536];          // current chunk: 2 d-slices [td][i][o]
    __shared__ uint4 REC[256][8];        // records [b_local][d_local]: wa, wb, i*512, 0

    const int t     = threadIdx.x;
    const int lane  = t & 63;
    const int wv    = t >> 6;            // 0..7
    const int p     = blockIdx.x & 7;    // d-group
    const int btile = blockIdx.x >> 3;   // 0..31
    const int dg    = p << 3;            // first d of group
    const int bbase = btile << 8;        // first b of tile

    // ---- issue async stage of chunk 0 (d = dg, dg+1 -> contiguous 64 KB) ----
    {
        const char* src = Tb + ((size_t)dg << 15);
        #pragma unroll
        for (int r = 0; r < 8; ++r) {
            __builtin_amdgcn_global_load_lds(
                (const uint32_t*)(src + t * 16 + r * 8192),
                (uint32_t*)(TL + t * 16 + r * 8192), 16, 0, 0);
        }
    }

    // ---- weight records: 4 per thread, overlapped with stage-0 latency ----
    #pragma unroll
    for (int k = 0; k < 4; ++k) {
        int r  = t + (k << 9);           // 0..2047
        int bl = r >> 3;                 // b_local 0..255
        int dl = r & 7;                  // d_local 0..7
        float xv = x[(bbase + bl) * 64 + dg + dl];
        float tt = (xv + 2.0f) * 15.75f;
        int i = (int)floorf(tt);
        i = i < 0 ? 0 : (i > 62 ? 62 : i);
        float u = tt - (float)i;
        float w1, w2, w3; uint32_t off;
        if (xv < -2.0f)      { w1 = tt;          w2 = 0.f;    w3 = 0.f;     off = 0u; }
        else if (xv > 2.0f)  { w1 = tt - 63.0f;  w2 = 0.f;    w3 = 0.f;     off = 63u << 9; }
        else                 { w1 = u;           w2 = u * u;  w3 = w2 * u;  off = (uint32_t)i << 9; }
        half2v wa; wa.x = (_Float16)1.0f; wa.y = (_Float16)w1;
        half2v wb; wb.x = (_Float16)w2;   wb.y = (_Float16)w3;
        REC[bl][dl] = make_uint4(__builtin_bit_cast(uint32_t, wa),
                                 __builtin_bit_cast(uint32_t, wb), off, 0u);
    }
    __syncthreads();   // implicit vmcnt(0)+lgkmcnt(0): chunk 0 staged, REC visible

    float acc[32];
    #pragma unroll
    for (int j = 0; j < 32; ++j) acc[j] = 0.0f;

    const int laneoff = lane << 3;
    for (int c = 0; c < 4; ++c) {        // 4 chunks x 2 d each
        const int c2 = c << 1;
        #pragma unroll
        for (int j = 0; j < 32; ++j) {
            int bl = (wv << 5) + j;
            uint4 r0 = REC[bl][c2 + 0];                          // uniform: broadcast
            uint4 r1 = REC[bl][c2 + 1];
            uint2 q0 = *(const uint2*)(TL + (r0.z + laneoff));   // 512B row, LDS
            uint2 q1 = *(const uint2*)(TL + (32768 + r1.z + laneoff));
            acc[j] = dot2acc(r0.x, q0.x, acc[j]);
            acc[j] = dot2acc(r0.y, q0.y, acc[j]);
            acc[j] = dot2acc(r1.x, q1.x, acc[j]);
            acc[j] = dot2acc(r1.y, q1.y, acc[j]);
        }
        if (c < 3) {
            __syncthreads();             // all waves done reading TL
            const char* src = Tb + ((size_t)(dg + c2 + 2) << 15);
            #pragma unroll
            for (int r = 0; r < 8; ++r) {
                __builtin_amdgcn_global_load_lds(
                    (const uint32_t*)(src + t * 16 + r * 8192),
                    (uint32_t*)(TL + t * 16 + r * 8192), 16, 0, 0);
            }
            __syncthreads();             // vmcnt(0) drained -> next chunk ready
        }
    }

    // ---- write partial plane p: part[p][b][o], coalesced ----
    float* dst = part + ((size_t)p * 8192 + bbase + (wv << 5)) * 64 + lane;
    #pragma unroll
    for (int j = 0; j < 32; ++j) {
        dst[j * 64] = acc[j];
    }
}

// Grid: 512 blocks x 256 threads. out = sum of 8 partial planes + bias.
__global__ void __launch_bounds__(256) kan_reduce(const float* __restrict__ part,
                                                  const float* __restrict__ bias,
                                                  float* __restrict__ out) {
    int idx = blockIdx.x * 256 + threadIdx.x;      // float4 index, 0..131071
    const float4* p4 = (const float4*)part;
    float4 s = p4[idx];
    #pragma unroll
    for (int pp = 1; pp < 8; ++pp) {
        float4 v = p4[(size_t)pp * 131072 + idx];
        s.x += v.x; s.y += v.y; s.z += v.z; s.w += v.w;
    }
    float4 bv = ((const float4*)bias)[idx & 15];
    s.x += bv.x; s.y += bv.y; s.z += bv.z; s.w += bv.w;
    ((float4*)out)[idx] = s;
}

extern "C" void kernel_launch(void* const* d_in, const int* in_sizes, int n_in,
                              void* d_out, int out_size, void* d_ws, size_t ws_size,
                              hipStream_t stream) {
    const float* x      = (const float*)d_in[0];   // [8192, 64]
    const float* coeffs = (const float*)d_in[1];   // [64, 64, 64]
    const float* bias   = (const float*)d_in[2];   // [64]
    float* out = (float*)d_out;                    // [8192, 64]

    uint2* T    = (uint2*)d_ws;                          // 2 MB table
    float* part = (float*)((char*)d_ws + (2u << 20));    // 16 MB partials [8][8192][64]

    build_table<<<dim3(256), dim3(256), 0, stream>>>(coeffs, T);
    kan_main<<<dim3(256), dim3(512), 0, stream>>>(x, (const char*)T, part);
    kan_reduce<<<dim3(512), dim3(256), 0, stream>>>(part, bias, out);
}

// Round 3
// 87.237 us; speedup vs baseline: 1.0732x; 1.0732x over previous
//
#include <hip/hip_runtime.h>
#include <hip/hip_fp16.h>
#include <stdint.h>

// ---------------------------------------------------------------------------
// BareKANLayer: out[b,o] = sum_d PCHIP_interp(x[b,d]; coeffs[o,d,:]) + bias[o]
// B=8192, O=64, D=64, K=64, grid [-2,2], h = 4/63.
//
// Table: per (d, interval i, o) cubic coeffs of p(u) = c0 + c1 u + c2 u^2 + c3 u^3
// packed as fp16 in a uint2: .x = (h(c1)<<16)|h(c0), .y = (h(c3)<<16)|h(c2).
// Row i=63 is a LINEAR row for right extrapolation. Left extrap = row 0, w2=w3=0.
// Layout: T[d][i][o], slice per d = 64*64*8 = 32 KB, total 2 MB in d_ws.
//
// Round-3: LDS-staged main (R2 concept) minus both R2 regression suspects:
//   - no 3rd kernel / no 16 MB partials: build_table bias-inits out,
//     kan_main atomicAdd's its d-group partial into out directly.
//   - double-buffered 32 KB chunks (1 d-slice each): staging latency hides
//     under compute, one barrier per chunk, smaller loop body.
// Block = 256 b's x 8 d's, 512 threads. LDS = 2x32 KB table + 32 KB records.
// ---------------------------------------------------------------------------

typedef _Float16 half2v __attribute__((ext_vector_type(2)));

#if defined(__has_builtin)
#if __has_builtin(__builtin_amdgcn_fdot2)
#define HAS_FDOT2 1
#endif
#endif

__device__ __forceinline__ uint32_t h16(float f) {
    return (uint32_t)__half_as_ushort(__float2half(f));   // RNE cvt
}

__device__ __forceinline__ float dot2acc(uint32_t a_bits, uint32_t b_bits, float acc) {
    half2v a = __builtin_bit_cast(half2v, a_bits);
    half2v b = __builtin_bit_cast(half2v, b_bits);
#ifdef HAS_FDOT2
    return __builtin_amdgcn_fdot2(a, b, acc, false);
#else
    return acc + (float)a.x * (float)b.x + (float)a.y * (float)b.y;
#endif
}

// Grid: 256 blocks (d = bx>>2, o-quarter = bx&3), 256 threads.
// Table build UNCHANGED; additionally bias-inits out (runs before kan_main
// on the stream, so kan_main's atomicAdd lands on initialized memory).
__global__ void build_table(const float* __restrict__ coeffs, uint2* __restrict__ T,
                            const float* __restrict__ bias, float* __restrict__ out) {
    const float hf = 4.0f / 63.0f;
    const float inv_hf = 63.0f / 4.0f;   // 15.75 exact in fp32
    int d  = blockIdx.x >> 2;
    int ob = (blockIdx.x & 3) << 4;      // base of this block's 16 o's
    __shared__ float Y[16][65];          // +1 pad: conflict-free
    int t = threadIdx.x;
    {
        int ol = t >> 4;                 // 0..15  (o local)
        int k4 = (t & 15) << 2;          // 0,4,...,60
        const float* src = coeffs + (size_t)(ob + ol) * 4096 + d * 64 + k4;
        float4 v = *(const float4*)src;  // 16B aligned
        Y[ol][k4 + 0] = v.x; Y[ol][k4 + 1] = v.y;
        Y[ol][k4 + 2] = v.z; Y[ol][k4 + 3] = v.w;
    }
    // ---- bias-init out: 2048 floats per block, coalesced ----
    {
        float bv = bias[t & 63];
        int g = blockIdx.x * 2048 + t;
        #pragma unroll
        for (int i = 0; i < 8; ++i) out[g + i * 256] = bv;
    }
    __syncthreads();
    for (int c = t; c < 1024; c += 256) {
        int ol = c & 15;
        int i  = c >> 4;                 // 0..63 (63 = linear extrapolation row)
        const float* Yr = Y[ol];
        auto delt = [&](int k) -> float { return (Yr[k + 1] - Yr[k]) * inv_hf; };
        auto endslope = [&](float a, float b) -> float {
            float de = (3.0f * a - b) * 0.5f;
            de = (de * a <= 0.0f) ? 0.0f : de;
            de = ((a * b < 0.0f) && (fabsf(de) > 3.0f * fabsf(a))) ? 3.0f * a : de;
            return de;
        };
        auto slope = [&](int k) -> float {
            if (k == 0)  return endslope(delt(0), delt(1));
            if (k == 63) return endslope(delt(62), delt(61));
            float dp = delt(k - 1), dn = delt(k);
            return (dp * dn > 0.0f) ? (2.0f * dp * dn) / (dp + dn + 1e-12f) : 0.0f;
        };
        uint2 pk;
        if (i < 63) {
            float y0 = Yr[i], y1 = Yr[i + 1];
            float di = slope(i), dj = slope(i + 1);
            float c0 = y0;
            float c1 = hf * di;
            float c2 = 3.0f * (y1 - y0) - hf * (2.0f * di + dj);
            float c3 = 2.0f * (y0 - y1) + hf * (di + dj);
            pk.x = (h16(c1) << 16) | h16(c0);
            pk.y = (h16(c3) << 16) | h16(c2);
        } else {
            float yN = Yr[63];
            float dN = slope(63);
            pk.x = (h16(hf * dN) << 16) | h16(yN);
            pk.y = 0u;
        }
        T[(size_t)d * 4096 + i * 64 + (ob + ol)] = pk;
    }
}

// Grid: 256 blocks x 512 threads (8 waves).
// Block: p = bx&7 -> d-group [8p, 8p+8); btile = bx>>3 -> 256 b's.
// Wave wv owns 32 b's; lane = o. 1-d chunks (32 KB) double-buffered in LDS.
__global__ void __launch_bounds__(512) kan_main(const float* __restrict__ x,
                                                const char* __restrict__ Tb,
                                                float* __restrict__ out) {
    __shared__ uint4 TLs[2][2048];       // 2 x 32 KB: chunk double-buffer
    __shared__ uint4 REC[256][8];        // records [b_local][d_local]: wa, wb, i*512, 0

    const int t     = threadIdx.x;
    const int lane  = t & 63;
    const int wv    = t >> 6;            // 0..7
    const int p     = blockIdx.x & 7;    // d-group
    const int btile = blockIdx.x >> 3;   // 0..31
    const int dg    = p << 3;            // first d of group
    const int bbase = btile << 8;        // first b of tile
    char* TL = (char*)TLs;

    // ---- issue async stage of chunk 0 (d = dg, 32 KB) into buffer 0 ----
    {
        const char* src = Tb + ((size_t)dg << 15);
        #pragma unroll
        for (int r = 0; r < 4; ++r) {
            __builtin_amdgcn_global_load_lds(
                (const uint32_t*)(src + t * 16 + r * 8192),
                (uint32_t*)(TL + t * 16 + r * 8192), 16, 0, 0);
        }
    }

    // ---- weight records: 4 per thread, overlapped with stage-0 latency ----
    #pragma unroll
    for (int k = 0; k < 4; ++k) {
        int r  = t + (k << 9);           // 0..2047
        int bl = r >> 3;                 // b_local 0..255
        int dl = r & 7;                  // d_local 0..7
        float xv = x[(bbase + bl) * 64 + dg + dl];
        float tt = (xv + 2.0f) * 15.75f;
        int i = (int)floorf(tt);
        i = i < 0 ? 0 : (i > 62 ? 62 : i);
        float u = tt - (float)i;
        float w1, w2, w3; uint32_t off;
        if (xv < -2.0f)      { w1 = tt;          w2 = 0.f;    w3 = 0.f;     off = 0u; }
        else if (xv > 2.0f)  { w1 = tt - 63.0f;  w2 = 0.f;    w3 = 0.f;     off = 63u << 9; }
        else                 { w1 = u;           w2 = u * u;  w3 = w2 * u;  off = (uint32_t)i << 9; }
        half2v wa; wa.x = (_Float16)1.0f; wa.y = (_Float16)w1;
        half2v wb; wb.x = (_Float16)w2;   wb.y = (_Float16)w3;
        REC[bl][dl] = make_uint4(__builtin_bit_cast(uint32_t, wa),
                                 __builtin_bit_cast(uint32_t, wb), off, 0u);
    }
    __syncthreads();   // vmcnt(0)+lgkmcnt(0): chunk 0 staged, REC visible

    float acc[32];
    #pragma unroll
    for (int j = 0; j < 32; ++j) acc[j] = 0.0f;

    const int laneoff = lane << 3;
    const int blbase  = wv << 5;
    for (int c = 0; c < 8; ++c) {        // 8 chunks x 1 d each, double-buffered
        // issue next chunk into the other buffer (WAR-safe: that buffer's
        // readers finished before the barrier that ended chunk c-1)
        if (c < 7) {
            const char* src = Tb + ((size_t)(dg + c + 1) << 15);
            char* dst = TL + ((c + 1) & 1) * 32768;
            #pragma unroll
            for (int r = 0; r < 4; ++r) {
                __builtin_amdgcn_global_load_lds(
                    (const uint32_t*)(src + t * 16 + r * 8192),
                    (uint32_t*)(dst + t * 16 + r * 8192), 16, 0, 0);
            }
        }
        const char* TLc = TL + (c & 1) * 32768;
        #pragma unroll
        for (int j = 0; j < 32; ++j) {
            uint4 r0 = REC[blbase + j][c];                      // uniform: broadcast
            uint2 q0 = *(const uint2*)(TLc + r0.z + laneoff);   // 512B row, LDS
            acc[j] = dot2acc(r0.x, q0.x, acc[j]);
            acc[j] = dot2acc(r0.y, q0.y, acc[j]);
        }
        __syncthreads();                 // drains vmcnt(0): next chunk ready
    }

    // ---- accumulate this block's d-group partial into out ----
    float* dst = out + (size_t)(bbase + blbase) * 64 + lane;
    #pragma unroll
    for (int j = 0; j < 32; ++j) {
        atomicAdd(dst + j * 64, acc[j]);
    }
}

extern "C" void kernel_launch(void* const* d_in, const int* in_sizes, int n_in,
                              void* d_out, int out_size, void* d_ws, size_t ws_size,
                              hipStream_t stream) {
    const float* x      = (const float*)d_in[0];   // [8192, 64]
    const float* coeffs = (const float*)d_in[1];   // [64, 64, 64]
    const float* bias   = (const float*)d_in[2];   // [64]
    float* out = (float*)d_out;                    // [8192, 64]

    uint2* T = (uint2*)d_ws;                       // 2 MB table
    build_table<<<dim3(256), dim3(256), 0, stream>>>(coeffs, T, bias, out);
    kan_main<<<dim3(256), dim3(512), 0, stream>>>(x, (const char*)T, out);
}

// Round 4
// 74.161 us; speedup vs baseline: 1.2624x; 1.1763x over previous
//
#include <hip/hip_runtime.h>
#include <hip/hip_fp16.h>
#include <stdint.h>

// ---------------------------------------------------------------------------
// BareKANLayer: out[b,o] = sum_d PCHIP_interp(x[b,d]; coeffs[o,d,:]) + bias[o]
// B=8192, O=64, D=64, K=64, grid [-2,2], h = 4/63.
//
// Table: per (d, interval i, o) cubic coeffs of p(u) = c0 + c1 u + c2 u^2 + c3 u^3
// packed as fp16 in a uint2: .x = (h(c1)<<16)|h(c0), .y = (h(c3)<<16)|h(c2).
// Row i=63 is a LINEAR row for right extrapolation. Left extrap = row 0, w2=w3=0.
// Layout: T[d][i][o], slice per d = 64*64*8 = 32 KB, total 2 MB in d_ws.
//
// Round-4: revert to the best structure (R0 gather, 79 us) and halve the
// wave-level vmem instruction count: each wave serves TWO b's per d-step.
// Lanes 0-31 = b0 (lane ol handles o=2ol,2ol+1), lanes 32-63 = b1. One
// dwordx4 gather per lane = 1024 B per wave-instruction (2 table rows).
// 524K -> 262K wave gathers; bytes/lines unchanged. Discriminates
// instruction-issue-limited vs L2-transaction-limited.
// Records are wave-private in LDS (no __syncthreads in kan_main at all).
// ---------------------------------------------------------------------------

typedef _Float16 half2v __attribute__((ext_vector_type(2)));

#if defined(__has_builtin)
#if __has_builtin(__builtin_amdgcn_fdot2)
#define HAS_FDOT2 1
#endif
#endif

__device__ __forceinline__ uint32_t h16(float f) {
    return (uint32_t)__half_as_ushort(__float2half(f));   // RNE cvt
}

__device__ __forceinline__ float dot2acc(uint32_t a_bits, uint32_t b_bits, float acc) {
    half2v a = __builtin_bit_cast(half2v, a_bits);
    half2v b = __builtin_bit_cast(half2v, b_bits);
#ifdef HAS_FDOT2
    return __builtin_amdgcn_fdot2(a, b, acc, false);
#else
    return acc + (float)a.x * (float)b.x + (float)a.y * (float)b.y;
#endif
}

// Grid: 256 blocks (d = bx>>2, o-quarter = bx&3), 256 threads.  (R0-identical)
__global__ void build_table(const float* __restrict__ coeffs, uint2* __restrict__ T) {
    const float hf = 4.0f / 63.0f;
    const float inv_hf = 63.0f / 4.0f;   // 15.75 exact in fp32
    int d  = blockIdx.x >> 2;
    int ob = (blockIdx.x & 3) << 4;      // base of this block's 16 o's
    __shared__ float Y[16][65];          // +1 pad: conflict-free
    int t = threadIdx.x;
    {
        int ol = t >> 4;                 // 0..15  (o local)
        int k4 = (t & 15) << 2;          // 0,4,...,60
        const float* src = coeffs + (size_t)(ob + ol) * 4096 + d * 64 + k4;
        float4 v = *(const float4*)src;  // 16B aligned
        Y[ol][k4 + 0] = v.x; Y[ol][k4 + 1] = v.y;
        Y[ol][k4 + 2] = v.z; Y[ol][k4 + 3] = v.w;
    }
    __syncthreads();
    for (int c = t; c < 1024; c += 256) {
        int ol = c & 15;
        int i  = c >> 4;                 // 0..63 (63 = linear extrapolation row)
        const float* Yr = Y[ol];
        auto delt = [&](int k) -> float { return (Yr[k + 1] - Yr[k]) * inv_hf; };
        auto endslope = [&](float a, float b) -> float {
            float de = (3.0f * a - b) * 0.5f;
            de = (de * a <= 0.0f) ? 0.0f : de;
            de = ((a * b < 0.0f) && (fabsf(de) > 3.0f * fabsf(a))) ? 3.0f * a : de;
            return de;
        };
        auto slope = [&](int k) -> float {
            if (k == 0)  return endslope(delt(0), delt(1));
            if (k == 63) return endslope(delt(62), delt(61));
            float dp = delt(k - 1), dn = delt(k);
            return (dp * dn > 0.0f) ? (2.0f * dp * dn) / (dp + dn + 1e-12f) : 0.0f;
        };
        uint2 pk;
        if (i < 63) {
            float y0 = Yr[i], y1 = Yr[i + 1];
            float di = slope(i), dj = slope(i + 1);
            float c0 = y0;
            float c1 = hf * di;
            float c2 = 3.0f * (y1 - y0) - hf * (2.0f * di + dj);
            float c3 = 2.0f * (y0 - y1) + hf * (di + dj);
            pk.x = (h16(c1) << 16) | h16(c0);
            pk.y = (h16(c3) << 16) | h16(c2);
        } else {
            float yN = Yr[63];
            float dN = slope(63);
            pk.x = (h16(hf * dN) << 16) | h16(yN);
            pk.y = 0u;
        }
        T[(size_t)d * 4096 + i * 64 + (ob + ol)] = pk;
    }
}

// Grid: 1024 blocks x 256 threads (4 waves). Wave wv serves b0 = bx*8+2wv,
// b1 = b0+1. Lane half h = lane>>5 -> b_h; ol = lane&31 -> o pair (2ol, 2ol+1).
__global__ void __launch_bounds__(256) kan_main(const float* __restrict__ x,
                                                const float* __restrict__ bias,
                                                const char* __restrict__ Tb,
                                                float* __restrict__ out) {
    __shared__ uint4 WL[8][64];          // 8 KB: records [b_local][d] (wave-private pairs)
    const int t     = threadIdx.x;
    const int lane  = t & 63;
    const int wv    = t >> 6;
    const int half  = lane >> 5;         // 0: b0, 1: b1
    const int ol    = lane & 31;         // o pair index
    const int bbase = blockIdx.x << 3;

    // ---- wave-private records: lane l builds (b0,d=l) and (b1,d=l) ----
    #pragma unroll
    for (int k = 0; k < 2; ++k) {
        int bl = (wv << 1) + k;
        float xv = x[(bbase + bl) * 64 + lane];
        float tt = (xv + 2.0f) * 15.75f;
        int i = (int)floorf(tt);
        i = i < 0 ? 0 : (i > 62 ? 62 : i);
        float u = tt - (float)i;
        float w1, w2, w3; uint32_t off;
        if (xv < -2.0f)      { w1 = tt;          w2 = 0.f;    w3 = 0.f;     off = 0u; }
        else if (xv > 2.0f)  { w1 = tt - 63.0f;  w2 = 0.f;    w3 = 0.f;     off = 63u << 9; }
        else                 { w1 = u;           w2 = u * u;  w3 = w2 * u;  off = (uint32_t)i << 9; }
        half2v wa; wa.x = (_Float16)1.0f; wa.y = (_Float16)w1;
        half2v wb; wb.x = (_Float16)w2;   wb.y = (_Float16)w3;
        WL[bl][lane] = make_uint4(__builtin_bit_cast(uint32_t, wa),
                                  __builtin_bit_cast(uint32_t, wb),
                                  ((uint32_t)lane << 15) | off, 0u);
    }
    // No __syncthreads: each wave reads only records it wrote (lgkmcnt orders).

    // ---- accumulate over d: one dwordx4 gather per lane (2 rows / wave) ----
    const uint4* rbase = &WL[(wv << 1) + half][0];
    const int laneoff = ol << 4;
    float ae0 = 0.0f, ae1 = 0.0f, ao0 = 0.0f, ao1 = 0.0f;
    #pragma unroll 8
    for (int d = 0; d < 64; ++d) {
        uint4 r = rbase[d];                              // 2-addr broadcast (free)
        uint4 q = *(const uint4*)(Tb + r.z + laneoff);   // 1KB/wave-instr, L2-hot
        ae0 = dot2acc(r.x, q.x, ae0);                    // o even
        ae1 = dot2acc(r.y, q.y, ae1);
        ao0 = dot2acc(r.x, q.z, ao0);                    // o odd
        ao1 = dot2acc(r.y, q.w, ao1);
    }

    // ---- epilogue: lane writes o-pair of its b ----
    float2 bv = ((const float2*)bias)[ol];
    float2 res;
    res.x = ae0 + ae1 + bv.x;
    res.y = ao0 + ao1 + bv.y;
    int b = bbase + (wv << 1) + half;
    ((float2*)(out + (size_t)b * 64))[ol] = res;
}

extern "C" void kernel_launch(void* const* d_in, const int* in_sizes, int n_in,
                              void* d_out, int out_size, void* d_ws, size_t ws_size,
                              hipStream_t stream) {
    const float* x      = (const float*)d_in[0];   // [8192, 64]
    const float* coeffs = (const float*)d_in[1];   // [64, 64, 64]
    const float* bias   = (const float*)d_in[2];   // [64]
    float* out = (float*)d_out;                    // [8192, 64]

    uint2* T = (uint2*)d_ws;                       // 2 MB table
    build_table<<<dim3(256), dim3(256), 0, stream>>>(coeffs, T);
    kan_main<<<dim3(1024), dim3(256), 0, stream>>>(x, bias, (const char*)d_ws, out);
}